// Round 6
// baseline (531.617 us; speedup 1.0000x reference)
//
#include <hip/hip_runtime.h>

#define B_ 8
#define C_ 256
#define I_ 128
#define N_ 4096
#define BN_ (B_ * N_)
#define LOG2E 1.4426950408889634f

typedef __attribute__((ext_vector_type(8))) short bf16x8;
typedef __attribute__((ext_vector_type(4))) float f32x4;
typedef __attribute__((ext_vector_type(2))) int i32x2;

static __device__ __forceinline__ short f2bf(float f) {
    unsigned u = __float_as_uint(f);
    unsigned r = u + 0x7fffu + ((u >> 16) & 1u);  // RNE
    return (short)(r >> 16);
}
static __device__ __forceinline__ float bf2f(short s) {
    return __uint_as_float(((unsigned)(unsigned short)s) << 16);
}
static __device__ __forceinline__ unsigned cvt_pk_bf16(float lo, float hi) {
    unsigned r;
    asm("v_cvt_pk_bf16_f32 %0, %1, %2" : "=v"(r) : "v"(lo), "v"(hi));
    return r;
}
// K=16 bf16 MFMA via asm (A,B: 2 VGPR; C/D: 4). A layout k=4q+e matches the
// S^T C-layout rows 4q+r directly -> P feeds PV with no cross-lane traffic.
static __device__ __forceinline__ f32x4 mfma16(i32x2 a, i32x2 b, f32x4 c) {
    asm("v_mfma_f32_16x16x16_bf16 %0, %1, %2, %0" : "+v"(c) : "v"(a), "v"(b));
    return c;
}

// ---------------- K0: weight prep (theta scaled by log2e) + bnsum zero -------
__global__ void k_prep(const float* g_w, const float* theta_w, const float* phi_w,
                       const float* g_b, const float* theta_b, const float* phi_b,
                       const float* w_w, short* wcat, short* wwb, float* bcat,
                       float* bnsum) {
    int i = blockIdx.x * 256 + threadIdx.x;
    if (i < 384 * 256) {
        int j = i >> 8, c = i & 255;
        float v = (j < 128) ? theta_w[j * 256 + c] * LOG2E
                : (j < 256) ? phi_w[(j - 128) * 256 + c]
                            : g_w[(j - 256) * 256 + c];
        wcat[i] = f2bf(v);
    } else if (i < 384 * 256 + 256 * 128) {
        int k = i - 384 * 256;
        wwb[k] = f2bf(w_w[k]);
    } else if (i < 384 * 256 + 256 * 128 + 384) {
        int j = i - (384 * 256 + 256 * 128);
        bcat[j] = (j < 128) ? theta_b[j] * LOG2E
                : (j < 256) ? phi_b[j - 128] : g_b[j - 256];
    } else if (i < 384 * 256 + 256 * 128 + 384 + 512) {
        bnsum[i - (384 * 256 + 256 * 128 + 384)] = 0.f;
    }
}

// ---------------- K1: projection -> tp[B][N][256], gmat[B][I][N] ---
__global__ __launch_bounds__(256) void k_proj(const float* __restrict__ x,
                                              const short* __restrict__ wcat,
                                              const float* __restrict__ bcat,
                                              short* __restrict__ tp,
                                              short* __restrict__ gmat) {
    int b = blockIdx.y;
    int n0 = blockIdx.x * 64;
    int tid = threadIdx.x;
    int wave = tid >> 6, lane = tid & 63, s = lane & 15, q = lane >> 4;
    __shared__ short xs[64][264];  // [n-local][c]

#pragma unroll
    for (int it = 0; it < 16; ++it) {
        int cr = (tid >> 4) + it * 16;
        int nc = tid & 15;
        const float4 v = *(const float4*)&x[((size_t)b * C_ + cr) * N_ + n0 + nc * 4];
        xs[nc * 4 + 0][cr] = f2bf(v.x);
        xs[nc * 4 + 1][cr] = f2bf(v.y);
        xs[nc * 4 + 2][cr] = f2bf(v.z);
        xs[nc * 4 + 3][cr] = f2bf(v.w);
    }
    __syncthreads();

    f32x4 acc[4][6];
#pragma unroll
    for (int rt = 0; rt < 4; ++rt)
#pragma unroll
        for (int jt = 0; jt < 6; ++jt) acc[rt][jt] = (f32x4){0.f, 0.f, 0.f, 0.f};

#pragma unroll
    for (int kb = 0; kb < 8; ++kb) {
        bf16x8 af[4], bfv[6];
#pragma unroll
        for (int rt = 0; rt < 4; ++rt)
            af[rt] = *(const bf16x8*)&xs[rt * 16 + s][kb * 32 + q * 8];
#pragma unroll
        for (int jt = 0; jt < 6; ++jt)
            bfv[jt] = *(const bf16x8*)&wcat[(wave * 96 + jt * 16 + s) * 256 + kb * 32 + q * 8];
#pragma unroll
        for (int rt = 0; rt < 4; ++rt)
#pragma unroll
            for (int jt = 0; jt < 6; ++jt)
                acc[rt][jt] = __builtin_amdgcn_mfma_f32_16x16x32_bf16(af[rt], bfv[jt], acc[rt][jt], 0, 0, 0);
    }

#pragma unroll
    for (int rt = 0; rt < 4; ++rt)
#pragma unroll
        for (int jt = 0; jt < 6; ++jt) {
            int j = wave * 96 + jt * 16 + s;
            float bias = bcat[j];
#pragma unroll
            for (int r = 0; r < 4; ++r) {
                int n = n0 + rt * 16 + 4 * q + r;
                float v = acc[rt][jt][r] + bias;
                if (j < 256)
                    tp[((size_t)b * N_ + n) * 256 + j] = f2bf(v);
                else
                    gmat[((size_t)b * I_ + (j - 256)) * N_ + n] = f2bf(v);
            }
        }
}

// ---- K2: fused flash attention + conv-out GEMM + BN-stat atomics ------------
// 256 blocks x 1024 threads (16 waves = 4 qg x 4 kg); Q-tile 128, all 4096
// keys, dbuf 128KB LDS (reg-staged, exact cover - R4 had 2x duplicate).
// Wave: 32 queries (fr=2) x 32-key slice (kg quarter of the 128-key tile).
// S^T = mfma(K,Q) 16x16x32; PV = 16x16x16 asm MFMA whose A-frag (k=4q+e)
// equals the S^T C-layout -> cvt_pk only, no permlane. 4 waves/SIMD.
// Epilogue: 2-stage tree kg-reduction (f32x4 LDS, swizzled) -> y bf16 ->
// in-block wy GEMM -> wyh + BN s1/s2 atomics.
__global__ __launch_bounds__(1024, 4) void k_attn_wy(const short* __restrict__ tp,
                                                     const short* __restrict__ gmat,
                                                     const short* __restrict__ wwb,
                                                     const float* __restrict__ w_b,
                                                     short* __restrict__ wyh,
                                                     float* __restrict__ bnsum) {
    int id = blockIdx.x;
    int b = id & 7;               // XCD swizzle: one batch's K/V per XCD L2
    int qt = id >> 3;             // 0..31
    int n0 = qt * 128;
    int tid = threadIdx.x;
    int wave = tid >> 6, lane = tid & 63, s = lane & 15, q = lane >> 4;
    int qg = wave & 3, kg = wave >> 2;

    // [buf0 64KB][buf1 64KB]; buf = Kt[128key][256B i] + Vt[128i][256B key]
    __shared__ __align__(16) short SH[65536];
    __shared__ float l_lds[4][128];
    char* base = (char*)SH;

    const int swz = (s & 7) << 4;
    int kA[4];
#pragma unroll
    for (int kb = 0; kb < 4; ++kb) kA[kb] = s * 256 + ((kb * 64 + q * 16) ^ swz);

    // staging: 1024 thr, 2 rounds of 64 rows (exact cover)
    int krow = tid >> 4, kch = tid & 15;  // 64 rows x 16 chunks
    int stW = krow * 256 + ((kch * 16) ^ ((krow & 7) << 4));

    // Q fragments (B-operand of S^T): queries n0 + qg*32 + fr*16 + s
    bf16x8 qf[2][4];
#pragma unroll
    for (int fr = 0; fr < 2; ++fr) {
        const short* qb = tp + ((size_t)b * N_ + n0 + qg * 32 + fr * 16 + s) * 256;
#pragma unroll
        for (int kb = 0; kb < 4; ++kb) qf[fr][kb] = *(const bf16x8*)(qb + kb * 32 + q * 8);
    }

    f32x4 ot[2][8];  // O partial (kg's 32-key slices): rows 4q+r, col i=t*16+s
#pragma unroll
    for (int fr = 0; fr < 2; ++fr)
#pragma unroll
        for (int t = 0; t < 8; ++t) ot[fr][t] = (f32x4){0.f, 0.f, 0.f, 0.f};
    float lsum[2] = {0.f, 0.f};

    // prologue: stage tile 0 into buf0
    bf16x8 pk[2], pv[2];
#pragma unroll
    for (int it = 0; it < 2; ++it) {
        pk[it] = *(const bf16x8*)&tp[((size_t)b * N_ + krow + it * 64) * 256 + 128 + kch * 8];
        pv[it] = *(const bf16x8*)&gmat[((size_t)b * I_ + krow + it * 64) * N_ + kch * 8];
    }
#pragma unroll
    for (int it = 0; it < 2; ++it) {
        *(bf16x8*)(base + stW + it * 16384) = pk[it];
        *(bf16x8*)(base + 32768 + stW + it * 16384) = pv[it];
    }
    __syncthreads();

    const int kgK = kg * 8192;   // Kt byte offset of kg's 32 keys
    const int kgV = kg * 64;     // Vt byte offset of kg's 32 keys

    for (int i = 0; i < 32; ++i) {
        char* KtB = base + (i & 1) * 65536;
        char* VtB = KtB + 32768;
        if (i < 31) {  // next-tile loads: issue early, hide under compute
            size_t m = (size_t)(i + 1) * 128;
#pragma unroll
            for (int it = 0; it < 2; ++it) {
                pk[it] = *(const bf16x8*)&tp[((size_t)b * N_ + m + krow + it * 64) * 256 + 128 + kch * 8];
                pv[it] = *(const bf16x8*)&gmat[((size_t)b * I_ + krow + it * 64) * N_ + m + kch * 8];
            }
        }

        // S^T = mfma(K, Q): sa[fr][tc][r] = P[key kg*32+tc*16+4q+r][query s]
        f32x4 sa[2][2];
#pragma unroll
        for (int fr = 0; fr < 2; ++fr)
#pragma unroll
            for (int tc = 0; tc < 2; ++tc) sa[fr][tc] = (f32x4){0.f, 0.f, 0.f, 0.f};
        __builtin_amdgcn_s_setprio(1);
#pragma unroll
        for (int tc = 0; tc < 2; ++tc) {
            bf16x8 bfv[4];
#pragma unroll
            for (int kb = 0; kb < 4; ++kb)
                bfv[kb] = *(const bf16x8*)(KtB + kgK + tc * 4096 + kA[kb]);
#pragma unroll
            for (int fr = 0; fr < 2; ++fr)
#pragma unroll
                for (int kb = 0; kb < 4; ++kb)
                    sa[fr][tc] = __builtin_amdgcn_mfma_f32_16x16x32_bf16(bfv[kb], qf[fr][kb], sa[fr][tc], 0, 0, 0);
        }
        __builtin_amdgcn_s_setprio(0);

        // P = exp2(S); l partial; pack pairs (keys 4q+{0,1}, 4q+{2,3})
        unsigned Wp[2][2][2];
#pragma unroll
        for (int fr = 0; fr < 2; ++fr) {
#pragma unroll
            for (int tc = 0; tc < 2; ++tc)
#pragma unroll
                for (int r = 0; r < 4; ++r) sa[fr][tc][r] = exp2f(sa[fr][tc][r]);
            lsum[fr] += ((sa[fr][0][0] + sa[fr][0][1]) + (sa[fr][0][2] + sa[fr][0][3]))
                      + ((sa[fr][1][0] + sa[fr][1][1]) + (sa[fr][1][2] + sa[fr][1][3]));
#pragma unroll
            for (int tc = 0; tc < 2; ++tc) {
                Wp[fr][tc][0] = cvt_pk_bf16(sa[fr][tc][0], sa[fr][tc][1]);
                Wp[fr][tc][1] = cvt_pk_bf16(sa[fr][tc][2], sa[fr][tc][3]);
            }
        }

        // PV: O += P^T V^T via 16x16x16 (A-frag = packed S^T output, direct)
        __builtin_amdgcn_s_setprio(1);
#pragma unroll
        for (int tc = 0; tc < 2; ++tc) {
            i32x2 pa0 = (i32x2){(int)Wp[0][tc][0], (int)Wp[0][tc][1]};
            i32x2 pa1 = (i32x2){(int)Wp[1][tc][0], (int)Wp[1][tc][1]};
#pragma unroll
            for (int t = 0; t < 8; ++t) {
                i32x2 vb = *(const i32x2*)(VtB + (t * 16 + s) * 256 + ((kgV + tc * 32 + q * 8) ^ swz));
                ot[0][t] = mfma16(pa0, vb, ot[0][t]);
                ot[1][t] = mfma16(pa1, vb, ot[1][t]);
            }
        }
        __builtin_amdgcn_s_setprio(0);

        if (i < 31) {  // write next tile into other buffer
            char* KtN = base + ((i & 1) ^ 1) * 65536;
#pragma unroll
            for (int it = 0; it < 2; ++it) {
                *(bf16x8*)(KtN + stW + it * 16384) = pk[it];
                *(bf16x8*)(KtN + 32768 + stW + it * 16384) = pv[it];
            }
        }
        __syncthreads();
    }

    // ---- epilogue ----
    // l: reduce over q lanes; publish per-kg partials
#pragma unroll
    for (int fr = 0; fr < 2; ++fr) {
        lsum[fr] += __shfl_xor(lsum[fr], 16);
        lsum[fr] += __shfl_xor(lsum[fr], 32);
    }
    if (q == 0) {
#pragma unroll
        for (int fr = 0; fr < 2; ++fr) l_lds[kg][qg * 32 + fr * 16 + s] = lsum[fr];
    }

    // 2-stage tree reduction of kg partials. O_T layout: i*512 + swz(row*4).
#define O_ADDR(D, i_, rb_) ((D) + (i_) * 512 + ((rb_) ^ (((i_) & 7) << 4)))
    if (kg == 1 || kg == 3) {
        char* D = base + (kg == 3 ? 65536 : 0);
#pragma unroll
        for (int fr = 0; fr < 2; ++fr)
#pragma unroll
            for (int t = 0; t < 8; ++t) {
                int ii = t * 16 + s;
                int rb = (qg * 32 + fr * 16 + 4 * q) * 4;
                *(f32x4*)O_ADDR(D, ii, rb) = ot[fr][t];
            }
    }
    __syncthreads();
    if (kg == 0 || kg == 2) {
        const char* D = base + (kg == 2 ? 65536 : 0);
#pragma unroll
        for (int fr = 0; fr < 2; ++fr)
#pragma unroll
            for (int t = 0; t < 8; ++t) {
                int ii = t * 16 + s;
                int rb = (qg * 32 + fr * 16 + 4 * q) * 4;
                ot[fr][t] += *(const f32x4*)O_ADDR(D, ii, rb);
            }
    }
    __syncthreads();
    if (kg == 2) {
#pragma unroll
        for (int fr = 0; fr < 2; ++fr)
#pragma unroll
            for (int t = 0; t < 8; ++t) {
                int ii = t * 16 + s;
                int rb = (qg * 32 + fr * 16 + 4 * q) * 4;
                *(f32x4*)O_ADDR(base, ii, rb) = ot[fr][t];
            }
    }
    __syncthreads();
    if (kg == 0) {
#pragma unroll
        for (int fr = 0; fr < 2; ++fr)
#pragma unroll
            for (int t = 0; t < 8; ++t) {
                int ii = t * 16 + s;
                int rb = (qg * 32 + fr * 16 + 4 * q) * 4;
                ot[fr][t] += *(const f32x4*)O_ADDR(base, ii, rb);
            }
        // write unnormalized y bf16 -> base[65536..98304), [row n][256B i] swz
#pragma unroll
        for (int fr = 0; fr < 2; ++fr)
#pragma unroll
            for (int t = 0; t < 8; ++t)
#pragma unroll
                for (int r = 0; r < 4; ++r) {
                    int row = qg * 32 + fr * 16 + 4 * q + r;
                    int byt = 65536 + row * 256 + (((t * 16 + s) * 2) ^ ((row & 7) << 4));
                    *(short*)(base + byt) = f2bf(ot[fr][t][r]);
                }
    }
    __syncthreads();
#undef O_ADDR

    // wy GEMM: c = wave*16 + {s|4q+r}, n = n0 + jt*16 + s
    f32x4 acc[8];
#pragma unroll
    for (int jt = 0; jt < 8; ++jt) acc[jt] = (f32x4){0.f, 0.f, 0.f, 0.f};
#pragma unroll
    for (int kb = 0; kb < 4; ++kb) {
        bf16x8 af = *(const bf16x8*)&wwb[(wave * 16 + s) * 128 + kb * 32 + q * 8];
#pragma unroll
        for (int jt = 0; jt < 8; ++jt) {
            bf16x8 yb = *(const bf16x8*)(base + 65536 + (jt * 16 + s) * 256 + ((kb * 64 + q * 16) ^ swz));
            acc[jt] = __builtin_amdgcn_mfma_f32_16x16x32_bf16(af, yb, acc[jt], 0, 0, 0);
        }
    }
    float linv[8];
#pragma unroll
    for (int jt = 0; jt < 8; ++jt) {
        int nl = jt * 16 + s;
        linv[jt] = 1.0f / (((l_lds[0][nl] + l_lds[1][nl]) + (l_lds[2][nl] + l_lds[3][nl])));
    }
#pragma unroll
    for (int r = 0; r < 4; ++r) {
        int c = wave * 16 + 4 * q + r;
        float bias = w_b[c];
        float s1 = 0.f, s2 = 0.f;
#pragma unroll
        for (int jt = 0; jt < 8; ++jt) {
            float v = acc[jt][r] * linv[jt] + bias;
            short w = f2bf(v);
            wyh[((size_t)b * C_ + c) * N_ + n0 + jt * 16 + s] = w;
            float vr = bf2f(w);
            s1 += vr;
            s2 += vr * vr;
        }
#pragma unroll
        for (int off = 1; off < 16; off <<= 1) {
            s1 += __shfl_xor(s1, off);
            s2 += __shfl_xor(s2, off);
        }
        if (s == 0) {
            atomicAdd(&bnsum[c], s1);
            atomicAdd(&bnsum[256 + c], s2);
        }
    }
}

// ---------------- K5: BN finalize + apply + residual -> d_out f32 ------------
__global__ __launch_bounds__(256) void k_out(const short* __restrict__ wyh,
                                             const float* __restrict__ x,
                                             const float* __restrict__ bnsum,
                                             const float* __restrict__ gamma,
                                             const float* __restrict__ beta,
                                             float* __restrict__ out) {
    int gid = blockIdx.x * 256 + threadIdx.x;  // 8-element group index
    size_t base = (size_t)gid * 8;
    int c = (int)((base >> 12) & 255);
    const float inv = 1.0f / 32768.0f;
    float mean = bnsum[c] * inv;
    float var = bnsum[256 + c] * inv - mean * mean;
    float sc = gamma[c] * rsqrtf(var + 1e-5f);
    float sh = beta[c] - mean * sc;
    bf16x8 w = *(const bf16x8*)&wyh[base];
    float4 x0 = *(const float4*)&x[base];
    float4 x1 = *(const float4*)&x[base + 4];
    float4 o0, o1;
    o0.x = bf2f(w[0]) * sc + sh + x0.x;
    o0.y = bf2f(w[1]) * sc + sh + x0.y;
    o0.z = bf2f(w[2]) * sc + sh + x0.z;
    o0.w = bf2f(w[3]) * sc + sh + x0.w;
    o1.x = bf2f(w[4]) * sc + sh + x1.x;
    o1.y = bf2f(w[5]) * sc + sh + x1.y;
    o1.z = bf2f(w[6]) * sc + sh + x1.z;
    o1.w = bf2f(w[7]) * sc + sh + x1.w;
    *(float4*)&out[base] = o0;
    *(float4*)&out[base + 4] = o1;
}

extern "C" void kernel_launch(void* const* d_in, const int* in_sizes, int n_in,
                              void* d_out, int out_size, void* d_ws, size_t ws_size,
                              hipStream_t stream) {
    const float* x       = (const float*)d_in[0];
    const float* g_w     = (const float*)d_in[1];
    const float* g_b     = (const float*)d_in[2];
    const float* theta_w = (const float*)d_in[3];
    const float* theta_b = (const float*)d_in[4];
    const float* phi_w   = (const float*)d_in[5];
    const float* phi_b   = (const float*)d_in[6];
    const float* w_w     = (const float*)d_in[7];
    const float* w_b     = (const float*)d_in[8];
    const float* gamma   = (const float*)d_in[9];
    const float* beta    = (const float*)d_in[10];

    char* ws = (char*)d_ws;
    size_t off = 0;
    auto alloc = [&](size_t bytes) {
        void* p = ws + off;
        off += (bytes + 255) & ~(size_t)255;
        return p;
    };
    short*  wcat  = (short*)alloc((size_t)384 * 256 * 2);
    short*  wwb   = (short*)alloc((size_t)256 * 128 * 2);
    float*  bcat  = (float*)alloc((size_t)384 * 4);
    float*  bnsum = (float*)alloc(512 * 4);                  // s1[256] | s2[256]
    short*  tp    = (short*)alloc((size_t)BN_ * 256 * 2);    // theta|phi 16.78 MB
    short*  gmat  = (short*)alloc((size_t)B_ * I_ * N_ * 2); // 8.39 MB
    short*  wyh   = (short*)alloc((size_t)BN_ * C_ * 2);     // bf16 wy 16.78 MB

    k_prep<<<516, 256, 0, stream>>>(g_w, theta_w, phi_w, g_b, theta_b, phi_b, w_w,
                                    wcat, wwb, bcat, bnsum);
    k_proj<<<dim3(64, 8), 256, 0, stream>>>(x, wcat, bcat, tp, gmat);
    k_attn_wy<<<256, 1024, 0, stream>>>(tp, gmat, wwb, w_b, wyh, bnsum);
    k_out<<<4096, 256, 0, stream>>>(wyh, x, bnsum, gamma, beta, (float*)d_out);
}

// Round 7
// 381.553 us; speedup vs baseline: 1.3933x; 1.3933x over previous
//
#include <hip/hip_runtime.h>

#define B_ 8
#define C_ 256
#define I_ 128
#define N_ 4096
#define BN_ (B_ * N_)
#define LOG2E 1.4426950408889634f

typedef __attribute__((ext_vector_type(8))) short bf16x8;
typedef __attribute__((ext_vector_type(4))) float f32x4;
typedef __attribute__((ext_vector_type(2))) int i32x2;

static __device__ __forceinline__ short f2bf(float f) {
    unsigned u = __float_as_uint(f);
    unsigned r = u + 0x7fffu + ((u >> 16) & 1u);  // RNE
    return (short)(r >> 16);
}
static __device__ __forceinline__ float bf2f(short s) {
    return __uint_as_float(((unsigned)(unsigned short)s) << 16);
}
static __device__ __forceinline__ unsigned cvt_pk_bf16(float lo, float hi) {
    unsigned r;
    asm("v_cvt_pk_bf16_f32 %0, %1, %2" : "=v"(r) : "v"(lo), "v"(hi));
    return r;
}
// K=16 bf16 MFMA (A,B: 2 VGPR; C/D: 4). A-frag k=4q+e matches the S^T
// C-layout rows 4q+r directly -> P feeds PV with no cross-lane traffic.
static __device__ __forceinline__ f32x4 mfma16(i32x2 a, i32x2 b, f32x4 c) {
    asm("v_mfma_f32_16x16x16_bf16 %0, %1, %2, %0" : "+v"(c) : "v"(a), "v"(b));
    return c;
}

// ---------------- K0: weight prep (theta scaled by log2e) + bnsum zero -------
__global__ void k_prep(const float* g_w, const float* theta_w, const float* phi_w,
                       const float* g_b, const float* theta_b, const float* phi_b,
                       const float* w_w, short* wcat, short* wwb, float* bcat,
                       float* bnsum) {
    int i = blockIdx.x * 256 + threadIdx.x;
    if (i < 384 * 256) {
        int j = i >> 8, c = i & 255;
        float v = (j < 128) ? theta_w[j * 256 + c] * LOG2E
                : (j < 256) ? phi_w[(j - 128) * 256 + c]
                            : g_w[(j - 256) * 256 + c];
        wcat[i] = f2bf(v);
    } else if (i < 384 * 256 + 256 * 128) {
        int k = i - 384 * 256;
        wwb[k] = f2bf(w_w[k]);
    } else if (i < 384 * 256 + 256 * 128 + 384) {
        int j = i - (384 * 256 + 256 * 128);
        bcat[j] = (j < 128) ? theta_b[j] * LOG2E
                : (j < 256) ? phi_b[j - 128] : g_b[j - 256];
    } else if (i < 384 * 256 + 256 * 128 + 384 + 512) {
        bnsum[i - (384 * 256 + 256 * 128 + 384)] = 0.f;
    }
}

// ---------------- K1: projection -> tp[B][N][256], gmat[B][I][N] ---
__global__ __launch_bounds__(256) void k_proj(const float* __restrict__ x,
                                              const short* __restrict__ wcat,
                                              const float* __restrict__ bcat,
                                              short* __restrict__ tp,
                                              short* __restrict__ gmat) {
    int b = blockIdx.y;
    int n0 = blockIdx.x * 64;
    int tid = threadIdx.x;
    int wave = tid >> 6, lane = tid & 63, s = lane & 15, q = lane >> 4;
    __shared__ short xs[64][264];  // [n-local][c]

#pragma unroll
    for (int it = 0; it < 16; ++it) {
        int cr = (tid >> 4) + it * 16;
        int nc = tid & 15;
        const float4 v = *(const float4*)&x[((size_t)b * C_ + cr) * N_ + n0 + nc * 4];
        xs[nc * 4 + 0][cr] = f2bf(v.x);
        xs[nc * 4 + 1][cr] = f2bf(v.y);
        xs[nc * 4 + 2][cr] = f2bf(v.z);
        xs[nc * 4 + 3][cr] = f2bf(v.w);
    }
    __syncthreads();

    f32x4 acc[4][6];
#pragma unroll
    for (int rt = 0; rt < 4; ++rt)
#pragma unroll
        for (int jt = 0; jt < 6; ++jt) acc[rt][jt] = (f32x4){0.f, 0.f, 0.f, 0.f};

#pragma unroll
    for (int kb = 0; kb < 8; ++kb) {
        bf16x8 af[4], bfv[6];
#pragma unroll
        for (int rt = 0; rt < 4; ++rt)
            af[rt] = *(const bf16x8*)&xs[rt * 16 + s][kb * 32 + q * 8];
#pragma unroll
        for (int jt = 0; jt < 6; ++jt)
            bfv[jt] = *(const bf16x8*)&wcat[(wave * 96 + jt * 16 + s) * 256 + kb * 32 + q * 8];
#pragma unroll
        for (int rt = 0; rt < 4; ++rt)
#pragma unroll
            for (int jt = 0; jt < 6; ++jt)
                acc[rt][jt] = __builtin_amdgcn_mfma_f32_16x16x32_bf16(af[rt], bfv[jt], acc[rt][jt], 0, 0, 0);
    }

#pragma unroll
    for (int rt = 0; rt < 4; ++rt)
#pragma unroll
        for (int jt = 0; jt < 6; ++jt) {
            int j = wave * 96 + jt * 16 + s;
            float bias = bcat[j];
#pragma unroll
            for (int r = 0; r < 4; ++r) {
                int n = n0 + rt * 16 + 4 * q + r;
                float v = acc[rt][jt][r] + bias;
                if (j < 256)
                    tp[((size_t)b * N_ + n) * 256 + j] = f2bf(v);
                else
                    gmat[((size_t)b * I_ + (j - 256)) * N_ + n] = f2bf(v);
            }
        }
}

// ---- K2: fused flash attention + conv-out GEMM + BN-stat atomics ------------
// 512 blocks x 512 threads (2 blocks/CU, 4 waves/SIMD); Q-tile 64, all 4096
// keys, M-tile 64, dbuf 64KB LDS (reg-staged). Waves: 2 qg (32 q, fr=2 keeps
// K-frag amortization) x 4 kg (16-key slices). S = mfma(K,Q) 16x16x32; PV =
// mfma16 (A-frag = packed S^T output; no permlane). Epilogue: 3-step kg tree
// reduction in LDS -> y bf16 -> in-block wy GEMM -> wyh + BN s1/s2 atomics.
__global__ __launch_bounds__(512, 4) void k_attn_wy(const short* __restrict__ tp,
                                                    const short* __restrict__ gmat,
                                                    const short* __restrict__ wwb,
                                                    const float* __restrict__ w_b,
                                                    short* __restrict__ wyh,
                                                    float* __restrict__ bnsum) {
    int id = blockIdx.x;
    int b = id & 7;               // XCD swizzle: one batch's K/V per XCD L2
    int qt = id >> 3;             // 0..63
    int n0 = qt * 64;
    int tid = threadIdx.x;
    int wave = tid >> 6, lane = tid & 63, s = lane & 15, q = lane >> 4;
    int qg = wave & 1, kg = wave >> 1;   // 2 qg x 4 kg

    // buf j at j*32768: Kt[64key][256B i] 16KB + Vt[128i][128B key] 16KB
    __shared__ __align__(16) short SH[32768];   // 64 KB
    __shared__ float l_lds[4][64];
    char* base = (char*)SH;

    const int swz = (s & 7) << 4;
    int kA[4];
#pragma unroll
    for (int kb = 0; kb < 4; ++kb) kA[kb] = s * 256 + ((kb * 64 + q * 16) ^ swz);
    const int vOff = (kg * 32 + q * 8) ^ swz;   // V read: +row(t*16+s)*128

    // staging coords: K 32rows x 16chunks x2 rounds; V 64rows x 8chunks x2
    int krow = tid >> 4, kch = tid & 15;
    int vrow = tid >> 3, vch = tid & 7;
    int stWk = krow * 256 + ((kch * 16) ^ ((krow & 7) << 4));
    int stWv = 16384 + vrow * 128 + ((vch * 16) ^ ((vrow & 7) << 4));

    // Q fragments (B-operand of S^T): queries n0 + qg*32 + fr*16 + s
    bf16x8 qf[2][4];
#pragma unroll
    for (int fr = 0; fr < 2; ++fr) {
        const short* qb = tp + ((size_t)b * N_ + n0 + qg * 32 + fr * 16 + s) * 256;
#pragma unroll
        for (int kb = 0; kb < 4; ++kb) qf[fr][kb] = *(const bf16x8*)(qb + kb * 32 + q * 8);
    }

    f32x4 ot[2][8];  // O partial (kg's 16-key slices): rows 4q+r, col i=t*16+s
#pragma unroll
    for (int fr = 0; fr < 2; ++fr)
#pragma unroll
        for (int t = 0; t < 8; ++t) ot[fr][t] = (f32x4){0.f, 0.f, 0.f, 0.f};
    float lsum[2] = {0.f, 0.f};

    // prologue: stage tile 0 into buf0
    bf16x8 pk[2], pv[2];
#pragma unroll
    for (int it = 0; it < 2; ++it) {
        pk[it] = *(const bf16x8*)&tp[((size_t)b * N_ + krow + it * 32) * 256 + 128 + kch * 8];
        pv[it] = *(const bf16x8*)&gmat[((size_t)b * I_ + vrow + it * 64) * N_ + vch * 8];
    }
#pragma unroll
    for (int it = 0; it < 2; ++it) {
        *(bf16x8*)(base + stWk + it * 8192) = pk[it];
        *(bf16x8*)(base + stWv + it * 8192) = pv[it];
    }
    __syncthreads();

    const int kgK = kg * 4096;   // Kt byte offset of kg's 16 keys

    for (int i = 0; i < 64; ++i) {
        char* KtB = base + (i & 1) * 32768;
        char* VtB = KtB + 16384;
        if (i < 63) {  // next-tile loads: issue early, hide under compute
            size_t m = (size_t)(i + 1) * 64;
#pragma unroll
            for (int it = 0; it < 2; ++it) {
                pk[it] = *(const bf16x8*)&tp[((size_t)b * N_ + m + krow + it * 32) * 256 + 128 + kch * 8];
                pv[it] = *(const bf16x8*)&gmat[((size_t)b * I_ + vrow + it * 64) * N_ + m + vch * 8];
            }
        }

        // S^T = mfma(K, Q): sa[fr][r] = P[key kg*16+4q+r][query fr*16+s]
        f32x4 sa[2];
        sa[0] = (f32x4){0.f, 0.f, 0.f, 0.f};
        sa[1] = (f32x4){0.f, 0.f, 0.f, 0.f};
        __builtin_amdgcn_s_setprio(1);
#pragma unroll
        for (int kb = 0; kb < 4; ++kb) {
            bf16x8 bfv = *(const bf16x8*)(KtB + kgK + kA[kb]);
            sa[0] = __builtin_amdgcn_mfma_f32_16x16x32_bf16(bfv, qf[0][kb], sa[0], 0, 0, 0);
            sa[1] = __builtin_amdgcn_mfma_f32_16x16x32_bf16(bfv, qf[1][kb], sa[1], 0, 0, 0);
        }
        __builtin_amdgcn_s_setprio(0);

        // P = exp2(S); l partial; pack to mfma16 A-frags (k = 4q+e)
        i32x2 pa[2];
#pragma unroll
        for (int fr = 0; fr < 2; ++fr) {
#pragma unroll
            for (int r = 0; r < 4; ++r) sa[fr][r] = exp2f(sa[fr][r]);
            lsum[fr] += (sa[fr][0] + sa[fr][1]) + (sa[fr][2] + sa[fr][3]);
            pa[fr] = (i32x2){(int)cvt_pk_bf16(sa[fr][0], sa[fr][1]),
                             (int)cvt_pk_bf16(sa[fr][2], sa[fr][3])};
        }

        // PV: O += P^T V^T via mfma16 (16 keys of this kg slice)
        __builtin_amdgcn_s_setprio(1);
#pragma unroll
        for (int t = 0; t < 8; ++t) {
            i32x2 vb = *(const i32x2*)(VtB + (t * 16 + s) * 128 + vOff);
            ot[0][t] = mfma16(pa[0], vb, ot[0][t]);
            ot[1][t] = mfma16(pa[1], vb, ot[1][t]);
        }
        __builtin_amdgcn_s_setprio(0);

        if (i < 63) {  // write next tile into other buffer
            char* Nd = base + ((i & 1) ^ 1) * 32768;
#pragma unroll
            for (int it = 0; it < 2; ++it) {
                *(bf16x8*)(Nd + stWk + it * 8192) = pk[it];
                *(bf16x8*)(Nd + stWv + it * 8192) = pv[it];
            }
        }
        __syncthreads();
    }

    // ---- epilogue: kg tree reduction, y->LDS, wy GEMM, BN atomics ----
    // l partials: reduce over q lanes, publish per kg
#pragma unroll
    for (int fr = 0; fr < 2; ++fr) {
        lsum[fr] += __shfl_xor(lsum[fr], 16);
        lsum[fr] += __shfl_xor(lsum[fr], 32);
    }
    if (q == 0) {
#pragma unroll
        for (int fr = 0; fr < 2; ++fr) l_lds[kg][qg * 32 + fr * 16 + s] = lsum[fr];
    }

    // O partial layout: ii*256 + swz(row*4); 32 KB per dump region
#define O_ADDR(D, ii_, rb_) ((D) + (ii_) * 256 + ((rb_) ^ (((ii_) & 7) << 4)))
    if (kg == 1 || kg == 3) {
        char* D = base + (kg == 3 ? 32768 : 0);
#pragma unroll
        for (int fr = 0; fr < 2; ++fr)
#pragma unroll
            for (int t = 0; t < 8; ++t) {
                int ii = t * 16 + s;
                int rb = (qg * 32 + fr * 16 + 4 * q) * 4;
                *(f32x4*)O_ADDR(D, ii, rb) = ot[fr][t];
            }
    }
    __syncthreads();
    if (kg == 0 || kg == 2) {
        const char* D = base + (kg == 2 ? 32768 : 0);
#pragma unroll
        for (int fr = 0; fr < 2; ++fr)
#pragma unroll
            for (int t = 0; t < 8; ++t) {
                int ii = t * 16 + s;
                int rb = (qg * 32 + fr * 16 + 4 * q) * 4;
                ot[fr][t] += *(const f32x4*)O_ADDR(D, ii, rb);
            }
    }
    __syncthreads();
    if (kg == 2) {
#pragma unroll
        for (int fr = 0; fr < 2; ++fr)
#pragma unroll
            for (int t = 0; t < 8; ++t) {
                int ii = t * 16 + s;
                int rb = (qg * 32 + fr * 16 + 4 * q) * 4;
                *(f32x4*)O_ADDR(base, ii, rb) = ot[fr][t];
            }
    }
    __syncthreads();
    if (kg == 0) {
#pragma unroll
        for (int fr = 0; fr < 2; ++fr)
#pragma unroll
            for (int t = 0; t < 8; ++t) {
                int ii = t * 16 + s;
                int rb = (qg * 32 + fr * 16 + 4 * q) * 4;
                ot[fr][t] += *(const f32x4*)O_ADDR(base, ii, rb);
            }
        // write unnormalized y bf16 -> base+32768, [64 n][256B i] swizzled
#pragma unroll
        for (int fr = 0; fr < 2; ++fr)
#pragma unroll
            for (int t = 0; t < 8; ++t)
#pragma unroll
                for (int r = 0; r < 4; ++r) {
                    int row = qg * 32 + fr * 16 + 4 * q + r;
                    int byt = 32768 + row * 256 + (((t * 16 + s) * 2) ^ ((row & 7) << 4));
                    *(short*)(base + byt) = f2bf(ot[fr][t][r]);
                }
    }
    __syncthreads();
#undef O_ADDR

    // wy GEMM: c = wave*32 + ct*16 + {s|4q+r}, n = n0 + jt*16 + s (jt<4)
    f32x4 acc[2][4];
#pragma unroll
    for (int ct = 0; ct < 2; ++ct)
#pragma unroll
        for (int jt = 0; jt < 4; ++jt) acc[ct][jt] = (f32x4){0.f, 0.f, 0.f, 0.f};
#pragma unroll
    for (int kb = 0; kb < 4; ++kb) {
        bf16x8 af[2];
#pragma unroll
        for (int ct = 0; ct < 2; ++ct)
            af[ct] = *(const bf16x8*)&wwb[(wave * 32 + ct * 16 + s) * 128 + kb * 32 + q * 8];
#pragma unroll
        for (int jt = 0; jt < 4; ++jt) {
            bf16x8 yb = *(const bf16x8*)(base + 32768 + (jt * 16 + s) * 256 + ((kb * 64 + q * 16) ^ swz));
#pragma unroll
            for (int ct = 0; ct < 2; ++ct)
                acc[ct][jt] = __builtin_amdgcn_mfma_f32_16x16x32_bf16(af[ct], yb, acc[ct][jt], 0, 0, 0);
        }
    }
    float linv[4];
#pragma unroll
    for (int jt = 0; jt < 4; ++jt) {
        int nl = jt * 16 + s;
        linv[jt] = 1.0f / ((l_lds[0][nl] + l_lds[1][nl]) + (l_lds[2][nl] + l_lds[3][nl]));
    }
#pragma unroll
    for (int ct = 0; ct < 2; ++ct)
#pragma unroll
        for (int r = 0; r < 4; ++r) {
            int c = wave * 32 + ct * 16 + 4 * q + r;
            float bias = w_b[c];
            float s1 = 0.f, s2 = 0.f;
#pragma unroll
            for (int jt = 0; jt < 4; ++jt) {
                float v = acc[ct][jt][r] * linv[jt] + bias;
                short w = f2bf(v);
                wyh[((size_t)b * C_ + c) * N_ + n0 + jt * 16 + s] = w;
                float vr = bf2f(w);
                s1 += vr;
                s2 += vr * vr;
            }
#pragma unroll
            for (int off = 1; off < 16; off <<= 1) {
                s1 += __shfl_xor(s1, off);
                s2 += __shfl_xor(s2, off);
            }
            if (s == 0) {
                atomicAdd(&bnsum[c], s1);
                atomicAdd(&bnsum[256 + c], s2);
            }
        }
}

// ---------------- K5: BN finalize + apply + residual -> d_out f32 ------------
__global__ __launch_bounds__(256) void k_out(const short* __restrict__ wyh,
                                             const float* __restrict__ x,
                                             const float* __restrict__ bnsum,
                                             const float* __restrict__ gamma,
                                             const float* __restrict__ beta,
                                             float* __restrict__ out) {
    int gid = blockIdx.x * 256 + threadIdx.x;  // 8-element group index
    size_t base = (size_t)gid * 8;
    int c = (int)((base >> 12) & 255);
    const float inv = 1.0f / 32768.0f;
    float mean = bnsum[c] * inv;
    float var = bnsum[256 + c] * inv - mean * mean;
    float sc = gamma[c] * rsqrtf(var + 1e-5f);
    float sh = beta[c] - mean * sc;
    bf16x8 w = *(const bf16x8*)&wyh[base];
    float4 x0 = *(const float4*)&x[base];
    float4 x1 = *(const float4*)&x[base + 4];
    float4 o0, o1;
    o0.x = bf2f(w[0]) * sc + sh + x0.x;
    o0.y = bf2f(w[1]) * sc + sh + x0.y;
    o0.z = bf2f(w[2]) * sc + sh + x0.z;
    o0.w = bf2f(w[3]) * sc + sh + x0.w;
    o1.x = bf2f(w[4]) * sc + sh + x1.x;
    o1.y = bf2f(w[5]) * sc + sh + x1.y;
    o1.z = bf2f(w[6]) * sc + sh + x1.z;
    o1.w = bf2f(w[7]) * sc + sh + x1.w;
    *(float4*)&out[base] = o0;
    *(float4*)&out[base + 4] = o1;
}

extern "C" void kernel_launch(void* const* d_in, const int* in_sizes, int n_in,
                              void* d_out, int out_size, void* d_ws, size_t ws_size,
                              hipStream_t stream) {
    const float* x       = (const float*)d_in[0];
    const float* g_w     = (const float*)d_in[1];
    const float* g_b     = (const float*)d_in[2];
    const float* theta_w = (const float*)d_in[3];
    const float* theta_b = (const float*)d_in[4];
    const float* phi_w   = (const float*)d_in[5];
    const float* phi_b   = (const float*)d_in[6];
    const float* w_w     = (const float*)d_in[7];
    const float* w_b     = (const float*)d_in[8];
    const float* gamma   = (const float*)d_in[9];
    const float* beta    = (const float*)d_in[10];

    char* ws = (char*)d_ws;
    size_t off = 0;
    auto alloc = [&](size_t bytes) {
        void* p = ws + off;
        off += (bytes + 255) & ~(size_t)255;
        return p;
    };
    short*  wcat  = (short*)alloc((size_t)384 * 256 * 2);
    short*  wwb   = (short*)alloc((size_t)256 * 128 * 2);
    float*  bcat  = (float*)alloc((size_t)384 * 4);
    float*  bnsum = (float*)alloc(512 * 4);                  // s1[256] | s2[256]
    short*  tp    = (short*)alloc((size_t)BN_ * 256 * 2);    // theta|phi 16.78 MB
    short*  gmat  = (short*)alloc((size_t)B_ * I_ * N_ * 2); // 8.39 MB
    short*  wyh   = (short*)alloc((size_t)BN_ * C_ * 2);     // bf16 wy 16.78 MB

    k_prep<<<516, 256, 0, stream>>>(g_w, theta_w, phi_w, g_b, theta_b, phi_b, w_w,
                                    wcat, wwb, bcat, bnsum);
    k_proj<<<dim3(64, 8), 256, 0, stream>>>(x, wcat, bcat, tp, gmat);
    k_attn_wy<<<512, 512, 0, stream>>>(tp, gmat, wwb, w_b, wyh, bnsum);  // 8b x 64qt
    k_out<<<4096, 256, 0, stream>>>(wyh, x, bnsum, gamma, beta, (float*)d_out);
}

// Round 9
// 272.101 us; speedup vs baseline: 1.9537x; 1.4023x over previous
//
#include <hip/hip_runtime.h>

#define B_ 8
#define C_ 256
#define I_ 128
#define N_ 4096
#define BN_ (B_ * N_)
#define LOG2E 1.4426950408889634f

typedef __attribute__((ext_vector_type(8))) short bf16x8;
typedef __attribute__((ext_vector_type(4))) float f32x4;
typedef __attribute__((ext_vector_type(2))) int i32x2;

static __device__ __forceinline__ short f2bf(float f) {
    unsigned u = __float_as_uint(f);
    unsigned r = u + 0x7fffu + ((u >> 16) & 1u);  // RNE
    return (short)(r >> 16);
}
static __device__ __forceinline__ float bf2f(short s) {
    return __uint_as_float(((unsigned)(unsigned short)s) << 16);
}
static __device__ __forceinline__ unsigned cvt_pk_bf16(float lo, float hi) {
    unsigned r;
    asm("v_cvt_pk_bf16_f32 %0, %1, %2" : "=v"(r) : "v"(lo), "v"(hi));
    return r;
}
// K=16 bf16 MFMA (A,B: 2 VGPR; C/D: 4). A-frag k=4q+e matches the S^T
// C-layout rows 4q+r directly -> P feeds PV with no cross-lane traffic.
// Layout-verified in R7 (passed correctness, absmax identical).
static __device__ __forceinline__ f32x4 mfma16(i32x2 a, i32x2 b, f32x4 c) {
    asm("v_mfma_f32_16x16x16_bf16 %0, %1, %2, %0" : "+v"(c) : "v"(a), "v"(b));
    return c;
}

// ---------------- K0: weight prep (theta scaled by log2e) + bnsum zero -------
__global__ void k_prep(const float* g_w, const float* theta_w, const float* phi_w,
                       const float* g_b, const float* theta_b, const float* phi_b,
                       const float* w_w, short* wcat, short* wwb, float* bcat,
                       float* bnsum) {
    int i = blockIdx.x * 256 + threadIdx.x;
    if (i < 384 * 256) {
        int j = i >> 8, c = i & 255;
        float v = (j < 128) ? theta_w[j * 256 + c] * LOG2E
                : (j < 256) ? phi_w[(j - 128) * 256 + c]
                            : g_w[(j - 256) * 256 + c];
        wcat[i] = f2bf(v);
    } else if (i < 384 * 256 + 256 * 128) {
        int k = i - 384 * 256;
        wwb[k] = f2bf(w_w[k]);
    } else if (i < 384 * 256 + 256 * 128 + 384) {
        int j = i - (384 * 256 + 256 * 128);
        bcat[j] = (j < 128) ? theta_b[j] * LOG2E
                : (j < 256) ? phi_b[j - 128] : g_b[j - 256];
    } else if (i < 384 * 256 + 256 * 128 + 384 + 512) {
        bnsum[i - (384 * 256 + 256 * 128 + 384)] = 0.f;
    }
}

// ---------------- K1: projection -> tp[B][N][256], gmat[B][I][N] ---
__global__ __launch_bounds__(256) void k_proj(const float* __restrict__ x,
                                              const short* __restrict__ wcat,
                                              const float* __restrict__ bcat,
                                              short* __restrict__ tp,
                                              short* __restrict__ gmat) {
    int b = blockIdx.y;
    int n0 = blockIdx.x * 64;
    int tid = threadIdx.x;
    int wave = tid >> 6, lane = tid & 63, s = lane & 15, q = lane >> 4;
    __shared__ short xs[64][264];  // [n-local][c]

#pragma unroll
    for (int it = 0; it < 16; ++it) {
        int cr = (tid >> 4) + it * 16;
        int nc = tid & 15;
        const float4 v = *(const float4*)&x[((size_t)b * C_ + cr) * N_ + n0 + nc * 4];
        xs[nc * 4 + 0][cr] = f2bf(v.x);
        xs[nc * 4 + 1][cr] = f2bf(v.y);
        xs[nc * 4 + 2][cr] = f2bf(v.z);
        xs[nc * 4 + 3][cr] = f2bf(v.w);
    }
    __syncthreads();

    f32x4 acc[4][6];
#pragma unroll
    for (int rt = 0; rt < 4; ++rt)
#pragma unroll
        for (int jt = 0; jt < 6; ++jt) acc[rt][jt] = (f32x4){0.f, 0.f, 0.f, 0.f};

#pragma unroll
    for (int kb = 0; kb < 8; ++kb) {
        bf16x8 af[4], bfv[6];
#pragma unroll
        for (int rt = 0; rt < 4; ++rt)
            af[rt] = *(const bf16x8*)&xs[rt * 16 + s][kb * 32 + q * 8];
#pragma unroll
        for (int jt = 0; jt < 6; ++jt)
            bfv[jt] = *(const bf16x8*)&wcat[(wave * 96 + jt * 16 + s) * 256 + kb * 32 + q * 8];
#pragma unroll
        for (int rt = 0; rt < 4; ++rt)
#pragma unroll
            for (int jt = 0; jt < 6; ++jt)
                acc[rt][jt] = __builtin_amdgcn_mfma_f32_16x16x32_bf16(af[rt], bfv[jt], acc[rt][jt], 0, 0, 0);
    }

#pragma unroll
    for (int rt = 0; rt < 4; ++rt)
#pragma unroll
        for (int jt = 0; jt < 6; ++jt) {
            int j = wave * 96 + jt * 16 + s;
            float bias = bcat[j];
#pragma unroll
            for (int r = 0; r < 4; ++r) {
                int n = n0 + rt * 16 + 4 * q + r;
                float v = acc[rt][jt][r] + bias;
                if (j < 256)
                    tp[((size_t)b * N_ + n) * 256 + j] = f2bf(v);
                else
                    gmat[((size_t)b * I_ + (j - 256)) * N_ + n] = f2bf(v);
            }
        }
}

// ---- K2: fused flash attention + conv-out GEMM + BN-stat atomics ------------
// 256 blocks x 1024 threads = 16 waves (8 qg x 2 kg), 4 waves/SIMD.
// fr=1 (16 q/wave) keeps per-wave loop state ~110 VGPR <= the 128 cap of
// __launch_bounds__(1024,4) -- the R6/R7 spill came from fr=2's qf32+ot64.
// Q-tile 128, M-tile 128, dbuf 128KB LDS (reg-staged, exact cover).
// S = mfma(K,Q) 16x16x32; PV = mfma16 (A-frag = packed S^T output, no
// permlane). Epilogue: kg=1 dumps O partials, kg=0 adds -> y bf16 ->
// in-block 16-wave wy GEMM -> wyh + BN s1/s2 atomics.
__global__ __launch_bounds__(1024, 4) void k_attn_wy(const short* __restrict__ tp,
                                                     const short* __restrict__ gmat,
                                                     const short* __restrict__ wwb,
                                                     const float* __restrict__ w_b,
                                                     short* __restrict__ wyh,
                                                     float* __restrict__ bnsum) {
    int id = blockIdx.x;
    int b = id & 7;               // XCD swizzle: one batch's K/V per XCD L2
    int qt = id >> 3;             // 0..31
    int n0 = qt * 128;
    int tid = threadIdx.x;
    int wave = tid >> 6, lane = tid & 63, s = lane & 15, q = lane >> 4;
    int qg = wave & 7, kg = wave >> 3;   // 8 qg x 2 kg

    // buf j at j*65536: Kt[128key][256B i] 32KB + Vt[128i][256B key] 32KB
    __shared__ __align__(16) short SH[65536];   // 128 KB
    __shared__ float l_lds[2][128];
    char* base = (char*)SH;

    const int swz = (s & 7) << 4;
    int kA[4];
#pragma unroll
    for (int kb = 0; kb < 4; ++kb) kA[kb] = s * 256 + ((kb * 64 + q * 16) ^ swz);

    // staging coords: 1024 thr; K/V each 64 rows x 16 chunks x 2 rounds
    int krow = tid >> 4, kch = tid & 15;
    int stWk = krow * 256 + ((kch * 16) ^ ((krow & 7) << 4));
    int stWv = 32768 + stWk;   // same geometry, Vt base

    // Q fragment (B-operand of S^T): queries n0 + qg*16 + s
    bf16x8 qf[4];
    {
        const short* qb = tp + ((size_t)b * N_ + n0 + qg * 16 + s) * 256;
#pragma unroll
        for (int kb = 0; kb < 4; ++kb) qf[kb] = *(const bf16x8*)(qb + kb * 32 + q * 8);
    }

    f32x4 ot[8];  // O partial (kg's 64-key half): rows=query 4q+r, col i=t*16+s
#pragma unroll
    for (int t = 0; t < 8; ++t) ot[t] = (f32x4){0.f, 0.f, 0.f, 0.f};
    float lsum = 0.f;

    // prologue: stage tile 0 into buf0
    bf16x8 pk[2], pv[2];
#pragma unroll
    for (int it = 0; it < 2; ++it) {
        pk[it] = *(const bf16x8*)&tp[((size_t)b * N_ + krow + it * 64) * 256 + 128 + kch * 8];
        pv[it] = *(const bf16x8*)&gmat[((size_t)b * I_ + krow + it * 64) * N_ + kch * 8];
    }
#pragma unroll
    for (int it = 0; it < 2; ++it) {
        *(bf16x8*)(base + stWk + it * 16384) = pk[it];
        *(bf16x8*)(base + stWv + it * 16384) = pv[it];
    }
    __syncthreads();

    const int kgK = kg * 16384;   // Kt byte offset of kg's 64 keys
    const int kgV = kg * 128;     // Vt byte offset of kg's 64 keys

    for (int i = 0; i < 32; ++i) {
        char* KtB = base + (i & 1) * 65536;
        char* VtB = KtB + 32768;
        if (i < 31) {  // next-tile loads: issue early, hide under compute
            size_t m = (size_t)(i + 1) * 128;
#pragma unroll
            for (int it = 0; it < 2; ++it) {
                pk[it] = *(const bf16x8*)&tp[((size_t)b * N_ + m + krow + it * 64) * 256 + 128 + kch * 8];
                pv[it] = *(const bf16x8*)&gmat[((size_t)b * I_ + krow + it * 64) * N_ + m + kch * 8];
            }
        }

        // S^T = mfma(K, Q): sa[tc][r] = P[key kg*64+tc*16+4q+r][query s]
        f32x4 sa[4];
#pragma unroll
        for (int tc = 0; tc < 4; ++tc) sa[tc] = (f32x4){0.f, 0.f, 0.f, 0.f};
        __builtin_amdgcn_s_setprio(1);
#pragma unroll
        for (int tc = 0; tc < 4; ++tc)
#pragma unroll
            for (int kb = 0; kb < 4; ++kb) {
                bf16x8 bfv = *(const bf16x8*)(KtB + kgK + tc * 4096 + kA[kb]);
                sa[tc] = __builtin_amdgcn_mfma_f32_16x16x32_bf16(bfv, qf[kb], sa[tc], 0, 0, 0);
            }
        __builtin_amdgcn_s_setprio(0);

        // P = exp2(S); l partial; pack to mfma16 A-frags (k = 4q+e)
        i32x2 pa[4];
#pragma unroll
        for (int tc = 0; tc < 4; ++tc) {
#pragma unroll
            for (int r = 0; r < 4; ++r) sa[tc][r] = exp2f(sa[tc][r]);
            lsum += (sa[tc][0] + sa[tc][1]) + (sa[tc][2] + sa[tc][3]);
            pa[tc] = (i32x2){(int)cvt_pk_bf16(sa[tc][0], sa[tc][1]),
                             (int)cvt_pk_bf16(sa[tc][2], sa[tc][3])};
        }

        // PV: O += P^T V^T via mfma16, 4 x 16-key sub-slices of kg's half
        __builtin_amdgcn_s_setprio(1);
#pragma unroll
        for (int tc = 0; tc < 4; ++tc)
#pragma unroll
            for (int t = 0; t < 8; ++t) {
                i32x2 vb = *(const i32x2*)(VtB + (t * 16 + s) * 256 + ((kgV + tc * 32 + q * 8) ^ swz));
                ot[t] = mfma16(pa[tc], vb, ot[t]);
            }
        __builtin_amdgcn_s_setprio(0);

        if (i < 31) {  // write next tile into other buffer
            char* Nd = base + ((i & 1) ^ 1) * 65536;
#pragma unroll
            for (int it = 0; it < 2; ++it) {
                *(bf16x8*)(Nd + stWk + it * 16384) = pk[it];
                *(bf16x8*)(Nd + stWv + it * 16384) = pv[it];
            }
        }
        __syncthreads();
    }

    // ---- epilogue: kg reduction, y->LDS, wy GEMM, BN atomics ----
    // l partial: reduce over q lanes; publish per kg
    lsum += __shfl_xor(lsum, 16);
    lsum += __shfl_xor(lsum, 32);
    if (q == 0) l_lds[kg][qg * 16 + s] = lsum;

    // O partial dump layout: per-qg 8KB region; addr = ii*64 + swz16(q*16)
#define O_ADDR(ii_, q_) (qg * 8192 + (ii_) * 64 + (((q_) * 16) ^ (((ii_) & 3) << 4)))
    if (kg == 1) {
#pragma unroll
        for (int t = 0; t < 8; ++t) {
            int ii = t * 16 + s;
            *(f32x4*)(base + O_ADDR(ii, q)) = ot[t];
        }
    }
    __syncthreads();
    if (kg == 0) {
#pragma unroll
        for (int t = 0; t < 8; ++t) {
            int ii = t * 16 + s;
            ot[t] += *(const f32x4*)(base + O_ADDR(ii, q));
        }
        // write unnormalized y bf16 -> base+65536, [128 n][256B i] swizzled
#pragma unroll
        for (int t = 0; t < 8; ++t)
#pragma unroll
            for (int r = 0; r < 4; ++r) {
                int row = qg * 16 + 4 * q + r;
                int byt = 65536 + row * 256 + (((t * 16 + s) * 2) ^ ((row & 7) << 4));
                *(short*)(base + byt) = f2bf(ot[t][r]);
            }
    }
    __syncthreads();
#undef O_ADDR

    // wy GEMM (16 waves): c = wave*16 + {s|4q+r}, n = n0 + jt*16 + s (jt<8)
    f32x4 acc[8];
#pragma unroll
    for (int jt = 0; jt < 8; ++jt) acc[jt] = (f32x4){0.f, 0.f, 0.f, 0.f};
#pragma unroll
    for (int kb = 0; kb < 4; ++kb) {
        bf16x8 af = *(const bf16x8*)&wwb[(wave * 16 + s) * 128 + kb * 32 + q * 8];
#pragma unroll
        for (int jt = 0; jt < 8; ++jt) {
            bf16x8 yb = *(const bf16x8*)(base + 65536 + (jt * 16 + s) * 256 + ((kb * 64 + q * 16) ^ swz));
            acc[jt] = __builtin_amdgcn_mfma_f32_16x16x32_bf16(af, yb, acc[jt], 0, 0, 0);
        }
    }
    float linv[8];
#pragma unroll
    for (int jt = 0; jt < 8; ++jt) {
        int nl = jt * 16 + s;
        linv[jt] = 1.0f / (l_lds[0][nl] + l_lds[1][nl]);
    }
#pragma unroll
    for (int r = 0; r < 4; ++r) {
        int c = wave * 16 + 4 * q + r;
        float bias = w_b[c];
        float s1 = 0.f, s2 = 0.f;
#pragma unroll
        for (int jt = 0; jt < 8; ++jt) {
            float v = acc[jt][r] * linv[jt] + bias;
            short w = f2bf(v);
            wyh[((size_t)b * C_ + c) * N_ + n0 + jt * 16 + s] = w;
            float vr = bf2f(w);
            s1 += vr;
            s2 += vr * vr;
        }
#pragma unroll
        for (int off = 1; off < 16; off <<= 1) {
            s1 += __shfl_xor(s1, off);
            s2 += __shfl_xor(s2, off);
        }
        if (s == 0) {
            atomicAdd(&bnsum[c], s1);
            atomicAdd(&bnsum[256 + c], s2);
        }
    }
}

// ---------------- K5: BN finalize + apply + residual -> d_out f32 ------------
__global__ __launch_bounds__(256) void k_out(const short* __restrict__ wyh,
                                             const float* __restrict__ x,
                                             const float* __restrict__ bnsum,
                                             const float* __restrict__ gamma,
                                             const float* __restrict__ beta,
                                             float* __restrict__ out) {
    int gid = blockIdx.x * 256 + threadIdx.x;  // 8-element group index
    size_t base = (size_t)gid * 8;
    int c = (int)((base >> 12) & 255);
    const float inv = 1.0f / 32768.0f;
    float mean = bnsum[c] * inv;
    float var = bnsum[256 + c] * inv - mean * mean;
    float sc = gamma[c] * rsqrtf(var + 1e-5f);
    float sh = beta[c] - mean * sc;
    bf16x8 w = *(const bf16x8*)&wyh[base];
    float4 x0 = *(const float4*)&x[base];
    float4 x1 = *(const float4*)&x[base + 4];
    float4 o0, o1;
    o0.x = bf2f(w[0]) * sc + sh + x0.x;
    o0.y = bf2f(w[1]) * sc + sh + x0.y;
    o0.z = bf2f(w[2]) * sc + sh + x0.z;
    o0.w = bf2f(w[3]) * sc + sh + x0.w;
    o1.x = bf2f(w[4]) * sc + sh + x1.x;
    o1.y = bf2f(w[5]) * sc + sh + x1.y;
    o1.z = bf2f(w[6]) * sc + sh + x1.z;
    o1.w = bf2f(w[7]) * sc + sh + x1.w;
    *(float4*)&out[base] = o0;
    *(float4*)&out[base + 4] = o1;
}

extern "C" void kernel_launch(void* const* d_in, const int* in_sizes, int n_in,
                              void* d_out, int out_size, void* d_ws, size_t ws_size,
                              hipStream_t stream) {
    const float* x       = (const float*)d_in[0];
    const float* g_w     = (const float*)d_in[1];
    const float* g_b     = (const float*)d_in[2];
    const float* theta_w = (const float*)d_in[3];
    const float* theta_b = (const float*)d_in[4];
    const float* phi_w   = (const float*)d_in[5];
    const float* phi_b   = (const float*)d_in[6];
    const float* w_w     = (const float*)d_in[7];
    const float* w_b     = (const float*)d_in[8];
    const float* gamma   = (const float*)d_in[9];
    const float* beta    = (const float*)d_in[10];

    char* ws = (char*)d_ws;
    size_t off = 0;
    auto alloc = [&](size_t bytes) {
        void* p = ws + off;
        off += (bytes + 255) & ~(size_t)255;
        return p;
    };
    short*  wcat  = (short*)alloc((size_t)384 * 256 * 2);
    short*  wwb   = (short*)alloc((size_t)256 * 128 * 2);
    float*  bcat  = (float*)alloc((size_t)384 * 4);
    float*  bnsum = (float*)alloc(512 * 4);                  // s1[256] | s2[256]
    short*  tp    = (short*)alloc((size_t)BN_ * 256 * 2);    // theta|phi 16.78 MB
    short*  gmat  = (short*)alloc((size_t)B_ * I_ * N_ * 2); // 8.39 MB
    short*  wyh   = (short*)alloc((size_t)BN_ * C_ * 2);     // bf16 wy 16.78 MB

    k_prep<<<516, 256, 0, stream>>>(g_w, theta_w, phi_w, g_b, theta_b, phi_b, w_w,
                                    wcat, wwb, bcat, bnsum);
    k_proj<<<dim3(64, 8), 256, 0, stream>>>(x, wcat, bcat, tp, gmat);
    k_attn_wy<<<256, 1024, 0, stream>>>(tp, gmat, wwb, w_b, wyh, bnsum);
    k_out<<<4096, 256, 0, stream>>>(wyh, x, bnsum, gamma, beta, (float*)d_out);
}

// Round 10
// 244.872 us; speedup vs baseline: 2.1710x; 1.1112x over previous
//
#include <hip/hip_runtime.h>

#define B_ 8
#define C_ 256
#define I_ 128
#define N_ 4096
#define BN_ (B_ * N_)
#define LOG2E 1.4426950408889634f

typedef __attribute__((ext_vector_type(8))) short bf16x8;
typedef __attribute__((ext_vector_type(4))) float f32x4;
typedef __attribute__((ext_vector_type(4))) int i32x4;

static __device__ __forceinline__ short f2bf(float f) {
    unsigned u = __float_as_uint(f);
    unsigned r = u + 0x7fffu + ((u >> 16) & 1u);  // RNE
    return (short)(r >> 16);
}
static __device__ __forceinline__ float bf2f(short s) {
    return __uint_as_float(((unsigned)(unsigned short)s) << 16);
}
static __device__ __forceinline__ unsigned cvt_pk_bf16(float lo, float hi) {
    unsigned r;
    asm("v_cvt_pk_bf16_f32 %0, %1, %2" : "=v"(r) : "v"(lo), "v"(hi));
    return r;
}

// ---------------- K0: weight prep (theta scaled by log2e) + bnsum zero -------
__global__ void k_prep(const float* g_w, const float* theta_w, const float* phi_w,
                       const float* g_b, const float* theta_b, const float* phi_b,
                       const float* w_w, short* wcat, short* wwb, float* bcat,
                       float* bnsum) {
    int i = blockIdx.x * 256 + threadIdx.x;
    if (i < 384 * 256) {
        int j = i >> 8, c = i & 255;
        float v = (j < 128) ? theta_w[j * 256 + c] * LOG2E
                : (j < 256) ? phi_w[(j - 128) * 256 + c]
                            : g_w[(j - 256) * 256 + c];
        wcat[i] = f2bf(v);
    } else if (i < 384 * 256 + 256 * 128) {
        int k = i - 384 * 256;
        wwb[k] = f2bf(w_w[k]);
    } else if (i < 384 * 256 + 256 * 128 + 384) {
        int j = i - (384 * 256 + 256 * 128);
        bcat[j] = (j < 128) ? theta_b[j] * LOG2E
                : (j < 256) ? phi_b[j - 128] : g_b[j - 256];
    } else if (i < 384 * 256 + 256 * 128 + 384 + 512) {
        bnsum[i - (384 * 256 + 256 * 128 + 384)] = 0.f;
    }
}

// ---------------- K1: projection -> tp[B][N][256], gmat[B][I][N] -------------
// v2: xs stride 258 (516B: staging writes 16-way -> ~4-way bank conflict,
// MFMA reads 8-way -> ~4-way). Epilogue bounces through LDS and writes tp as
// one contiguous 32KB block (dwordx4, 1KB/wave/instr) and gmat as 128B rows —
// replaces 96 scalar 2B global stores per thread.
__global__ __launch_bounds__(256) void k_proj(const float* __restrict__ x,
                                              const short* __restrict__ wcat,
                                              const float* __restrict__ bcat,
                                              short* __restrict__ tp,
                                              short* __restrict__ gmat) {
    int b = blockIdx.y;
    int n0 = blockIdx.x * 64;
    int tid = threadIdx.x;
    int wave = tid >> 6, lane = tid & 63, s = lane & 15, q = lane >> 4;
    __shared__ __align__(16) char SM[33024];  // xs[64][258] | ytile | gtile
    short (*xs)[258] = (short(*)[258])SM;

#pragma unroll
    for (int it = 0; it < 16; ++it) {
        int cr = (tid >> 4) + it * 16;
        int nc = tid & 15;
        const float4 v = *(const float4*)&x[((size_t)b * C_ + cr) * N_ + n0 + nc * 4];
        xs[nc * 4 + 0][cr] = f2bf(v.x);
        xs[nc * 4 + 1][cr] = f2bf(v.y);
        xs[nc * 4 + 2][cr] = f2bf(v.z);
        xs[nc * 4 + 3][cr] = f2bf(v.w);
    }
    __syncthreads();

    f32x4 acc[4][6];
#pragma unroll
    for (int rt = 0; rt < 4; ++rt)
#pragma unroll
        for (int jt = 0; jt < 6; ++jt) acc[rt][jt] = (f32x4){0.f, 0.f, 0.f, 0.f};

#pragma unroll
    for (int kb = 0; kb < 8; ++kb) {
        bf16x8 af[4], bfv[6];
#pragma unroll
        for (int rt = 0; rt < 4; ++rt)
            af[rt] = *(const bf16x8*)&xs[rt * 16 + s][kb * 32 + q * 8];
#pragma unroll
        for (int jt = 0; jt < 6; ++jt)
            bfv[jt] = *(const bf16x8*)&wcat[(wave * 96 + jt * 16 + s) * 256 + kb * 32 + q * 8];
#pragma unroll
        for (int rt = 0; rt < 4; ++rt)
#pragma unroll
            for (int jt = 0; jt < 6; ++jt)
                acc[rt][jt] = __builtin_amdgcn_mfma_f32_16x16x32_bf16(af[rt], bfv[jt], acc[rt][jt], 0, 0, 0);
    }
    __syncthreads();  // xs dead; reuse SM

    // ---- Phase A: tp (j < 256) via ytile[64][256] bounce ----
    short* ytile = (short*)SM;
#pragma unroll
    for (int jt = 0; jt < 6; ++jt) {
        int j = wave * 96 + jt * 16 + s;
        if (j < 256) {
            float bias = bcat[j];
#pragma unroll
            for (int rt = 0; rt < 4; ++rt)
#pragma unroll
                for (int r = 0; r < 4; ++r)
                    ytile[(rt * 16 + 4 * q + r) * 256 + j] = f2bf(acc[rt][jt][r] + bias);
        }
    }
    __syncthreads();
    {
        short* dst = tp + ((size_t)b * N_ + n0) * 256;
#pragma unroll
        for (int k = 0; k < 8; ++k) {
            int off = k * 2048 + tid * 8;
            *(bf16x8*)(dst + off) = *(const bf16x8*)(ytile + off);
        }
    }
    __syncthreads();

    // ---- Phase B: gmat (j >= 256) via gtile[128][66] bounce ----
    short* gt = (short*)SM;  // stride 66 shorts (132B): scalar writes ~2-way
#pragma unroll
    for (int jt = 0; jt < 6; ++jt) {
        int j = wave * 96 + jt * 16 + s;
        if (j >= 256) {
            float bias = bcat[j];
            int i2 = j - 256;
#pragma unroll
            for (int rt = 0; rt < 4; ++rt)
#pragma unroll
                for (int r = 0; r < 4; ++r)
                    gt[i2 * 66 + rt * 16 + 4 * q + r] = f2bf(acc[rt][jt][r] + bias);
        }
    }
    __syncthreads();
#pragma unroll
    for (int k = 0; k < 4; ++k) {
        int idx = k * 256 + tid;      // 1024 chunks of 8 shorts
        int i2 = idx >> 3, nch = idx & 7;
        bf16x8 v = *(const bf16x8*)(gt + i2 * 66 + nch * 8);
        *(bf16x8*)&gmat[((size_t)b * I_ + i2) * N_ + n0 + nch * 8] = v;
    }
}

// ---- K2: fused flash attention + conv-out GEMM + BN-stat atomics ------------
// R4-core (proven 104us): 256 blocks x 512 threads; Q-tile 128, all 4096 keys,
// dbuf 128KB LDS, reg staging. Waves: 4 qg (32 q, fr=2) x 2 kg (64-key half).
// S^T = mfma(K,Q); P via cvt_pk + permlane swaps; l via ones-MFMA.
// Epilogue (R5-proven): kg cross-reduction -> y bf16 -> in-block wy GEMM ->
// wyh + per-channel BN s1/s2 shfl-reduce + atomicAdd into bnsum.
__global__ __launch_bounds__(512, 2) void k_attn_wy(const short* __restrict__ tp,
                                                    const short* __restrict__ gmat,
                                                    const short* __restrict__ wwb,
                                                    const float* __restrict__ w_b,
                                                    short* __restrict__ wyh,
                                                    float* __restrict__ bnsum) {
    int id = blockIdx.x;
    int b = id & 7;               // XCD swizzle: one batch's K/V per XCD L2
    int qt = id >> 3;             // 0..31
    int n0 = qt * 128;
    int tid = threadIdx.x;
    int wave = tid >> 6, lane = tid & 63, s = lane & 15, q = lane >> 4;
    int kg = wave >> 2, qg = wave & 3;

    // 2 bufs x (Kt[128key][128i] 32KB + Vt[128i][128key] 32KB) = 128KB, swizzled
    __shared__ __align__(16) short SH[65536];
    __shared__ float l_lds[2][128];
    char* base = (char*)SH;

    const int swz = (s & 7) << 4;
    int kA[4];
#pragma unroll
    for (int kb = 0; kb < 4; ++kb) kA[kb] = s * 256 + ((kb * 64 + q * 16) ^ swz);
    int vA[2];
#pragma unroll
    for (int kb2 = 0; kb2 < 2; ++kb2) vA[kb2] = s * 256 + ((kb2 * 64 + q * 16) ^ swz);
    int krow = tid >> 4, kch = tid & 15;  // staging: 32 rows x 16 chunks
    int stW = krow * 256 + ((kch * 16) ^ ((krow & 7) << 4));

    // ones B-frag for l-accumulation MFMA
    i32x4 onesw = (i32x4){0x3F803F80, 0x3F803F80, 0x3F803F80, 0x3F803F80};
    bf16x8 vone = __builtin_bit_cast(bf16x8, onesw);

    // Q fragments (B-operand of S^T): queries n0 + qg*32 + fr*16 + s
    bf16x8 qf[2][4];
#pragma unroll
    for (int fr = 0; fr < 2; ++fr) {
        const short* qb = tp + ((size_t)b * N_ + n0 + qg * 32 + fr * 16 + s) * 256;
#pragma unroll
        for (int kb = 0; kb < 4; ++kb) qf[fr][kb] = *(const bf16x8*)(qb + kb * 32 + q * 8);
    }

    f32x4 ot[2][8];  // O partial (kg's key half): rows=query 4q+r, cols i=t*16+s
#pragma unroll
    for (int fr = 0; fr < 2; ++fr)
#pragma unroll
        for (int t = 0; t < 8; ++t) ot[fr][t] = (f32x4){0.f, 0.f, 0.f, 0.f};
    f32x4 lacc[2] = {(f32x4){0.f, 0.f, 0.f, 0.f}, (f32x4){0.f, 0.f, 0.f, 0.f}};

    // prologue: stage tile 0 into buf0 (reg staging; exact cover rows 0..127)
    bf16x8 pk[4], pv[4];
#pragma unroll
    for (int it = 0; it < 4; ++it) {
        pk[it] = *(const bf16x8*)&tp[((size_t)b * N_ + krow + it * 32) * 256 + 128 + kch * 8];
        pv[it] = *(const bf16x8*)&gmat[((size_t)b * I_ + krow + it * 32) * N_ + kch * 8];
    }
#pragma unroll
    for (int it = 0; it < 4; ++it) {
        *(bf16x8*)(base + stW + it * 8192) = pk[it];
        *(bf16x8*)(base + 32768 + stW + it * 8192) = pv[it];
    }
    __syncthreads();

    const int hK = kg * 16384, hV = kg * 128;  // this wave's 64-key half

    for (int i = 0; i < 32; ++i) {
        char* KtB = base + (i & 1) * 65536;
        char* VtB = KtB + 32768;
        if (i < 31) {  // issue next-tile loads early; latency hides under compute
            size_t m = (size_t)(i + 1) * 128;
#pragma unroll
            for (int it = 0; it < 4; ++it) {
                pk[it] = *(const bf16x8*)&tp[((size_t)b * N_ + m + krow + it * 32) * 256 + 128 + kch * 8];
                pv[it] = *(const bf16x8*)&gmat[((size_t)b * I_ + krow + it * 32) * N_ + m + kch * 8];
            }
        }

        // S^T = mfma(K, Q): D[row=key kg*64+tc*16+4q+r][col=query s]
        f32x4 sa[2][4];
#pragma unroll
        for (int fr = 0; fr < 2; ++fr)
#pragma unroll
            for (int tc = 0; tc < 4; ++tc) sa[fr][tc] = (f32x4){0.f, 0.f, 0.f, 0.f};
        __builtin_amdgcn_s_setprio(1);
#pragma unroll
        for (int tc = 0; tc < 4; ++tc) {
            bf16x8 bfv[4];
#pragma unroll
            for (int kb = 0; kb < 4; ++kb)
                bfv[kb] = *(const bf16x8*)(KtB + hK + kA[kb] + tc * 4096);
#pragma unroll
            for (int fr = 0; fr < 2; ++fr)
#pragma unroll
                for (int kb = 0; kb < 4; ++kb)
                    sa[fr][tc] = __builtin_amdgcn_mfma_f32_16x16x32_bf16(bfv[kb], qf[fr][kb], sa[fr][tc], 0, 0, 0);
        }
        __builtin_amdgcn_s_setprio(0);

        // P = exp2(S), pack pairs (keys 2p,2p+1)
        unsigned W[2][4][2];
#pragma unroll
        for (int fr = 0; fr < 2; ++fr) {
#pragma unroll
            for (int tc = 0; tc < 4; ++tc)
#pragma unroll
                for (int r = 0; r < 4; ++r) sa[fr][tc][r] = exp2f(sa[fr][tc][r]);
#pragma unroll
            for (int tc = 0; tc < 4; ++tc) {
                W[fr][tc][0] = cvt_pk_bf16(sa[fr][tc][0], sa[fr][tc][1]);
                W[fr][tc][1] = cvt_pk_bf16(sa[fr][tc][2], sa[fr][tc][3]);
            }
        }

        // PV: redistribute P pairs in-register; l via ones-MFMA; O += P*V^T
#pragma unroll
        for (int kb2 = 0; kb2 < 2; ++kb2) {
            bf16x8 pa[2];
#pragma unroll
            for (int fr = 0; fr < 2; ++fr) {
                unsigned rA = W[fr][2 * kb2 + 0][0];
                unsigned rB = W[fr][2 * kb2 + 0][1];
                unsigned rC = W[fr][2 * kb2 + 1][0];
                unsigned rD = W[fr][2 * kb2 + 1][1];
                asm("v_permlane32_swap_b32 %0, %1" : "+v"(rA), "+v"(rC));
                asm("v_permlane32_swap_b32 %0, %1" : "+v"(rB), "+v"(rD));
                asm("v_permlane16_swap_b32 %0, %1" : "+v"(rA), "+v"(rC));
                asm("v_permlane16_swap_b32 %0, %1" : "+v"(rB), "+v"(rD));
                i32x4 wv = (i32x4){(int)rA, (int)rB, (int)rC, (int)rD};
                pa[fr] = __builtin_bit_cast(bf16x8, wv);
            }
            __builtin_amdgcn_s_setprio(1);
            lacc[0] = __builtin_amdgcn_mfma_f32_16x16x32_bf16(pa[0], vone, lacc[0], 0, 0, 0);
            lacc[1] = __builtin_amdgcn_mfma_f32_16x16x32_bf16(pa[1], vone, lacc[1], 0, 0, 0);
#pragma unroll
            for (int t = 0; t < 8; ++t) {
                bf16x8 vb = *(const bf16x8*)(VtB + hV + vA[kb2] + t * 4096);
                ot[0][t] = __builtin_amdgcn_mfma_f32_16x16x32_bf16(pa[0], vb, ot[0][t], 0, 0, 0);
                ot[1][t] = __builtin_amdgcn_mfma_f32_16x16x32_bf16(pa[1], vb, ot[1][t], 0, 0, 0);
            }
            __builtin_amdgcn_s_setprio(0);
        }

        if (i < 31) {  // write next tile into other buffer
            char* KtN = base + ((i & 1) ^ 1) * 65536;
#pragma unroll
            for (int it = 0; it < 4; ++it) {
                *(bf16x8*)(KtN + stW + it * 8192) = pk[it];
                *(bf16x8*)(KtN + 32768 + stW + it * 8192) = pv[it];
            }
        }
        __syncthreads();
    }

    // ---- epilogue: cross-kg O reduction, y->LDS, in-block wy GEMM ----
    // l: all cols of lacc are equal; lane s==0 publishes rows 4q+r
    if (s == 0) {
#pragma unroll
        for (int fr = 0; fr < 2; ++fr)
#pragma unroll
            for (int r = 0; r < 4; ++r)
                l_lds[kg][qg * 32 + fr * 16 + 4 * q + r] = lacc[fr][r];
    }
    // kg=1 dumps O partials (f32, swizzled 16B blocks) into base[0..64KB)
    if (kg == 1) {
#pragma unroll
        for (int fr = 0; fr < 2; ++fr)
#pragma unroll
            for (int t = 0; t < 8; ++t)
#pragma unroll
                for (int r = 0; r < 4; ++r) {
                    int row = qg * 32 + fr * 16 + 4 * q + r;
                    int colb = (t * 16 + s) * 4;
                    *(float*)(base + row * 512 + (colb ^ ((row & 7) << 4))) = ot[fr][t][r];
                }
    }
    __syncthreads();
    // kg=0 adds partials, writes unnormalized y bf16 -> base[65536..98304)
    if (kg == 0) {
#pragma unroll
        for (int fr = 0; fr < 2; ++fr)
#pragma unroll
            for (int t = 0; t < 8; ++t)
#pragma unroll
                for (int r = 0; r < 4; ++r) {
                    int row = qg * 32 + fr * 16 + 4 * q + r;
                    int colb = (t * 16 + s) * 4;
                    float p = *(const float*)(base + row * 512 + (colb ^ ((row & 7) << 4)));
                    float v = ot[fr][t][r] + p;
                    int byt = 65536 + row * 256 + (((t * 16 + s) * 2) ^ ((row & 7) << 4));
                    *(short*)(base + byt) = f2bf(v);
                }
    }
    __syncthreads();

    // wy GEMM: c = wave*32 + ct*16 + {s|4q+r}, n = n0 + jt*16 + s
    f32x4 acc[2][8];
#pragma unroll
    for (int ct = 0; ct < 2; ++ct)
#pragma unroll
        for (int jt = 0; jt < 8; ++jt) acc[ct][jt] = (f32x4){0.f, 0.f, 0.f, 0.f};
#pragma unroll
    for (int kb = 0; kb < 4; ++kb) {
        bf16x8 af[2];
#pragma unroll
        for (int ct = 0; ct < 2; ++ct)
            af[ct] = *(const bf16x8*)&wwb[(wave * 32 + ct * 16 + s) * 128 + kb * 32 + q * 8];
#pragma unroll
        for (int jt = 0; jt < 8; ++jt) {
            bf16x8 yb = *(const bf16x8*)(base + 65536 + kA[kb] + jt * 4096);
#pragma unroll
            for (int ct = 0; ct < 2; ++ct)
                acc[ct][jt] = __builtin_amdgcn_mfma_f32_16x16x32_bf16(af[ct], yb, acc[ct][jt], 0, 0, 0);
        }
    }
    float linv[8];
#pragma unroll
    for (int jt = 0; jt < 8; ++jt)
        linv[jt] = 1.0f / (l_lds[0][jt * 16 + s] + l_lds[1][jt * 16 + s]);
#pragma unroll
    for (int ct = 0; ct < 2; ++ct)
#pragma unroll
        for (int r = 0; r < 4; ++r) {
            int c = wave * 32 + ct * 16 + 4 * q + r;
            float bias = w_b[c];
            float s1 = 0.f, s2 = 0.f;
#pragma unroll
            for (int jt = 0; jt < 8; ++jt) {
                float v = acc[ct][jt][r] * linv[jt] + bias;
                short w = f2bf(v);
                wyh[((size_t)b * C_ + c) * N_ + n0 + jt * 16 + s] = w;
                float vr = bf2f(w);   // stats on rounded value == old k_stats
                s1 += vr;
                s2 += vr * vr;
            }
#pragma unroll
            for (int off = 1; off < 16; off <<= 1) {
                s1 += __shfl_xor(s1, off);
                s2 += __shfl_xor(s2, off);
            }
            if (s == 0) {
                atomicAdd(&bnsum[c], s1);
                atomicAdd(&bnsum[256 + c], s2);
            }
        }
}

// ---------------- K5: BN finalize + apply + residual -> d_out f32 ------------
__global__ __launch_bounds__(256) void k_out(const short* __restrict__ wyh,
                                             const float* __restrict__ x,
                                             const float* __restrict__ bnsum,
                                             const float* __restrict__ gamma,
                                             const float* __restrict__ beta,
                                             float* __restrict__ out) {
    int gid = blockIdx.x * 256 + threadIdx.x;  // 8-element group index
    size_t base = (size_t)gid * 8;
    int c = (int)((base >> 12) & 255);
    const float inv = 1.0f / 32768.0f;
    float mean = bnsum[c] * inv;
    float var = bnsum[256 + c] * inv - mean * mean;
    float sc = gamma[c] * rsqrtf(var + 1e-5f);
    float sh = beta[c] - mean * sc;
    bf16x8 w = *(const bf16x8*)&wyh[base];
    float4 x0 = *(const float4*)&x[base];
    float4 x1 = *(const float4*)&x[base + 4];
    float4 o0, o1;
    o0.x = bf2f(w[0]) * sc + sh + x0.x;
    o0.y = bf2f(w[1]) * sc + sh + x0.y;
    o0.z = bf2f(w[2]) * sc + sh + x0.z;
    o0.w = bf2f(w[3]) * sc + sh + x0.w;
    o1.x = bf2f(w[4]) * sc + sh + x1.x;
    o1.y = bf2f(w[5]) * sc + sh + x1.y;
    o1.z = bf2f(w[6]) * sc + sh + x1.z;
    o1.w = bf2f(w[7]) * sc + sh + x1.w;
    *(float4*)&out[base] = o0;
    *(float4*)&out[base + 4] = o1;
}

extern "C" void kernel_launch(void* const* d_in, const int* in_sizes, int n_in,
                              void* d_out, int out_size, void* d_ws, size_t ws_size,
                              hipStream_t stream) {
    const float* x       = (const float*)d_in[0];
    const float* g_w     = (const float*)d_in[1];
    const float* g_b     = (const float*)d_in[2];
    const float* theta_w = (const float*)d_in[3];
    const float* theta_b = (const float*)d_in[4];
    const float* phi_w   = (const float*)d_in[5];
    const float* phi_b   = (const float*)d_in[6];
    const float* w_w     = (const float*)d_in[7];
    const float* w_b     = (const float*)d_in[8];
    const float* gamma   = (const float*)d_in[9];
    const float* beta    = (const float*)d_in[10];

    char* ws = (char*)d_ws;
    size_t off = 0;
    auto alloc = [&](size_t bytes) {
        void* p = ws + off;
        off += (bytes + 255) & ~(size_t)255;
        return p;
    };
    short*  wcat  = (short*)alloc((size_t)384 * 256 * 2);
    short*  wwb   = (short*)alloc((size_t)256 * 128 * 2);
    float*  bcat  = (float*)alloc((size_t)384 * 4);
    float*  bnsum = (float*)alloc(512 * 4);                  // s1[256] | s2[256]
    short*  tp    = (short*)alloc((size_t)BN_ * 256 * 2);    // theta|phi 16.78 MB
    short*  gmat  = (short*)alloc((size_t)B_ * I_ * N_ * 2); // 8.39 MB
    short*  wyh   = (short*)alloc((size_t)BN_ * C_ * 2);     // bf16 wy 16.78 MB

    k_prep<<<516, 256, 0, stream>>>(g_w, theta_w, phi_w, g_b, theta_b, phi_b, w_w,
                                    wcat, wwb, bcat, bnsum);
    k_proj<<<dim3(64, 8), 256, 0, stream>>>(x, wcat, bcat, tp, gmat);
    k_attn_wy<<<256, 512, 0, stream>>>(tp, gmat, wwb, w_b, wyh, bnsum);
    k_out<<<4096, 256, 0, stream>>>(wyh, x, bnsum, gamma, beta, (float*)d_out);
}